// Round 2
// 5862.880 us; speedup vs baseline: 1.1220x; 1.1220x over previous
//
#include <hip/hip_runtime.h>

#define NUM_Q 8
#define D     1024
#define CDIM  32
#define K     1024
#define B     16
#define T     4096
#define QC    (NUM_Q*CDIM)   // 256

// ---------------- K0a: normalized codebook (fp64), matches ref l2norm ----------------
__global__ void k_cbn(const float* __restrict__ cb, double* __restrict__ cbn) {
  int i = blockIdx.x*blockDim.x + threadIdx.x;   // q*K + k
  if (i >= NUM_Q*K) return;
  const float* v = cb + (size_t)i*CDIM;
  double s = 0.0;
  for (int c = 0; c < CDIM; ++c) { double x = (double)v[c]; s += x*x; }
  double n = sqrt(s);
  n = fmax(n, 1e-12);
  double* o = cbn + (size_t)i*CDIM;
  for (int c = 0; c < CDIM; ++c) o[c] = (double)v[c] / n;
}

// ---------------- K0b: zero loss accumulators + sum of out_b over stages ----------------
__global__ void k_prep(const float* __restrict__ out_b, double* __restrict__ obsum,
                       double* __restrict__ lossAcc) {
  int i = blockIdx.x*blockDim.x + threadIdx.x;
  if (i < NUM_Q) lossAcc[i] = 0.0;
  if (i < D) {
    double s = 0.0;
    for (int q = 0; q < NUM_Q; ++q) s += (double)out_b[q*D + i];
    obsum[i] = s;
  }
}

// ---------------- K0c: fp64 copy of in_w (enables scalar s_load weights in k_P) --------
__global__ void k_w64(const float* __restrict__ in_w, double* __restrict__ w64) {
  int i = blockIdx.x*blockDim.x + threadIdx.x;   // QC*D = 262144
  if (i < QC*D) w64[i] = (double)in_w[i];
}

// ---------------- K1a: M[q][p] = in_w[q] @ out_w[p]  (32x32, fp64), vb = in_w[q]@out_b[p] ----
__global__ void k_M(const float* __restrict__ in_w, const float* __restrict__ out_w,
                    const float* __restrict__ out_b, double* __restrict__ M,
                    double* __restrict__ vb) {
  int i = blockIdx.x*blockDim.x + threadIdx.x;   // 8*8*32*32 = 65536
  int e = i & 31; int c = (i >> 5) & 31; int p = (i >> 10) & 7; int q = i >> 13;
  if (q >= NUM_Q) return;
  const float* wi = in_w + ((size_t)q*CDIM + c)*D;
  const float* wo = out_w + (size_t)p*D*CDIM + e;
  double s = 0.0;
  for (int d = 0; d < D; ++d) s += (double)wi[d] * (double)wo[(size_t)d*CDIM];
  M[i] = s;
  if (e == 0) {
    const float* ob = out_b + (size_t)p*D;
    double sb = 0.0;
    for (int d = 0; d < D; ++d) sb += (double)wi[d] * (double)ob[d];
    vb[(q*8 + p)*CDIM + c] = sb;
  }
}

// ---------------- K1b: Mcb[q][p][k][c] = sum_e M[q][p][c][e] * cb[p][k][e] ----------------
// only pairs with 1<=q, p<q are ever read by k_stage; q==0 slabs are repurposed as w64.
__global__ void k_Mcb(const double* __restrict__ M, const float* __restrict__ cb,
                      double* __restrict__ Mcb) {
  long i = blockIdx.x*(long)blockDim.x + threadIdx.x;  // 8*8*1024*32 = 2097152
  if (i >= (long)NUM_Q*NUM_Q*K*CDIM) return;
  int c = (int)(i & 31); long r = i >> 5;
  int k = (int)(r & (K-1)); r >>= 10;
  int p = (int)(r & 7); int q = (int)(r >> 3);
  if (q == 0 || p >= q) return;                        // unused slabs (q=0 region = w64)
  const double* m = M + (((size_t)(q*8 + p)*CDIM + c)*CDIM);
  const float* v = cb + ((size_t)p*K + k)*CDIM;
  double s = 0.0;
  for (int e = 0; e < CDIM; ++e) s += m[e] * (double)v[e];
  Mcb[((size_t)(q*8 + p)*K + k)*CDIM + c] = s;
}

// ---------------- K2: P[b][j][t] = sum_d w64[j][d] * x[b][d][t]  (fp64 accum) --------
// weights read via wave-uniform address -> scalar s_load path; no LDS.
__global__ __launch_bounds__(256, 4) void k_P(const float* __restrict__ x,
                                              const double* __restrict__ w64,
                                              double* __restrict__ P) {
  int j0 = blockIdx.x*32;                 // j-tile (x fastest -> L2 reuse of x tile)
  int t  = blockIdx.y*256 + threadIdx.x;
  int b  = blockIdx.z;
  double acc[32];
  #pragma unroll
  for (int j = 0; j < 32; ++j) acc[j] = 0.0;
  const float* xp = x + (size_t)b*D*T + t;
  #pragma unroll 2
  for (int d = 0; d < D; d += 2) {
    double xv0 = (double)xp[(size_t)d*T];
    double xv1 = (double)xp[(size_t)(d+1)*T];
    #pragma unroll
    for (int jj = 0; jj < 32; ++jj) {
      double2 w = *(const double2*)(w64 + (size_t)(j0 + jj)*D + d);
      acc[jj] += xv0 * w.x;
      acc[jj] += xv1 * w.y;
    }
  }
  double* Pp = P + ((size_t)b*QC + j0)*T + t;
  #pragma unroll
  for (int jj = 0; jj < 32; ++jj) Pp[(size_t)jj*T] = acc[jj];
}

// ---------------- K3: per-stage fused correction + argmax + zq + loss ----------
// 4-way k-split (sg = wave-uniform group), 512-thread blocks -> 4 waves/SIMD.
// normalization dropped: argmax(z.r) == argmax((z/n).r) since n>0; loss uses raw z.
__global__ __launch_bounds__(512, 4) void k_stage(
    int q,
    const double* __restrict__ P, const double* __restrict__ Mcb,
    const double* __restrict__ vb, const float* __restrict__ in_b,
    const double* __restrict__ cbn, const float* __restrict__ cb,
    int* __restrict__ idx_ws, float* __restrict__ zq,
    double* __restrict__ lossAcc, float* __restrict__ out_idx) {
  __shared__ double bs[4][128];
  __shared__ int    bkk[4][128];
  const int tt = threadIdx.x & 127;
  const int sg = threadIdx.x >> 7;        // 0..3, uniform per wave
  const int i  = blockIdx.x*128 + tt;     // b*T + t
  const int b  = i >> 12;
  const int t  = i & (T-1);

  double z[CDIM];
  {
    const double* Pp = P + ((size_t)b*QC + q*CDIM)*T + t;
    #pragma unroll
    for (int c = 0; c < CDIM; ++c) z[c] = Pp[(size_t)c*T] + (double)in_b[q*CDIM + c];
  }
  for (int p = 0; p < q; ++p) {
    int kp = idx_ws[(size_t)p*B*T + i];
    const double* mc  = Mcb + ((size_t)(q*8 + p)*K + kp)*CDIM;
    const double* vbp = vb + (q*8 + p)*CDIM;
    #pragma unroll
    for (int c = 0; c < CDIM; ++c) z[c] -= (mc[c] + vbp[c]);
  }

  const double* cbq = cbn + ((size_t)q*K + (size_t)sg*(K/4))*CDIM;
  double best = -1e300; int bi = 0;
  for (int k = 0; k < K/4; ++k) {
    const double* r = cbq + (size_t)k*CDIM;
    double s0 = 0.0, s1 = 0.0, s2 = 0.0, s3 = 0.0;
    #pragma unroll
    for (int c = 0; c < CDIM; c += 4) {
      s0 += z[c]*r[c]; s1 += z[c+1]*r[c+1];
      s2 += z[c+2]*r[c+2]; s3 += z[c+3]*r[c+3];
    }
    double sim = (s0 + s1) + (s2 + s3);
    if (sim > best) { best = sim; bi = k; }   // strict > == first-occurrence in group
  }
  bs[sg][tt]  = best;
  bkk[sg][tt] = sg*(K/4) + bi;
  __syncthreads();

  if (sg == 0) {
    double bb = bs[0][tt]; int kbest = bkk[0][tt];
    #pragma unroll
    for (int g = 1; g < 4; ++g) {            // ascending group + strict > == global
      if (bs[g][tt] > bb) { bb = bs[g][tt]; kbest = bkk[g][tt]; }   // first-occurrence
    }
    idx_ws[(size_t)q*B*T + i] = kbest;
    out_idx[(size_t)q*B*T + i] = (float)kbest;

    const float* cv = cb + ((size_t)q*K + kbest)*CDIM;
    float* zp = zq + ((size_t)b*QC + q*CDIM)*T + t;
    double l = 0.0;
    #pragma unroll
    for (int c = 0; c < CDIM; ++c) {
      float f = cv[c];
      zp[(size_t)c*T] = f;
      double d2 = z[c] - (double)f;
      l += d2*d2;
    }
    for (int off = 32; off > 0; off >>= 1) l += __shfl_down(l, off, 64);
    if ((threadIdx.x & 63) == 0) atomicAdd(&lossAcc[q], l);
  }
}

// ---------------- K4: quantized_out = out_w_cat @ zq_cat + obsum  (fp32) -------------------
#define TT 4
__global__ __launch_bounds__(256) void k_out(const float* __restrict__ zq,
                                             const float* __restrict__ out_w,
                                             const double* __restrict__ obsum,
                                             float* __restrict__ out) {
  __shared__ float lw[QC][16];            // 16 KB, [j][d-sub] -> b128 broadcast reads
  int d0 = blockIdx.x*16;                 // d-tile on x -> consecutive blocks reuse zq tile
  int t0 = blockIdx.y*(256*TT);
  int b  = blockIdx.z;
  for (int u = threadIdx.x; u < 16*QC; u += 256) {
    int j = u >> 4; int a = u & 15;
    lw[j][a] = out_w[(size_t)(j >> 5)*D*CDIM + (size_t)(d0 + a)*CDIM + (j & 31)];
  }
  __syncthreads();
  float acc[16][TT];
  #pragma unroll
  for (int a = 0; a < 16; ++a)
    #pragma unroll
    for (int u = 0; u < TT; ++u) acc[a][u] = 0.f;
  const float* zp = zq + (size_t)b*QC*T + t0 + threadIdx.x;
  for (int j = 0; j < QC; ++j) {
    float zv[TT];
    #pragma unroll
    for (int u = 0; u < TT; ++u) zv[u] = zp[(size_t)j*T + u*256];
    #pragma unroll
    for (int a4 = 0; a4 < 4; ++a4) {
      float4 w = *(const float4*)&lw[j][a4*4];
      #pragma unroll
      for (int u = 0; u < TT; ++u) {
        acc[a4*4+0][u] += w.x*zv[u];
        acc[a4*4+1][u] += w.y*zv[u];
        acc[a4*4+2][u] += w.z*zv[u];
        acc[a4*4+3][u] += w.w*zv[u];
      }
    }
  }
  for (int a = 0; a < 16; ++a) {
    float bb = (float)obsum[d0 + a];
    float* op = out + ((size_t)b*D + d0 + a)*T + t0 + threadIdx.x;
    #pragma unroll
    for (int u = 0; u < TT; ++u) op[(size_t)u*256] = acc[a][u] + bb;
  }
}

// ---------------- K5: losses -> d_out ----------------
__global__ void k_loss(const double* __restrict__ lossAcc, float* __restrict__ out_l) {
  int i = threadIdx.x;
  if (i < NUM_Q)
    out_l[i] = (float)(1.25 * lossAcc[i] / ((double)B * CDIM * T));
}

extern "C" void kernel_launch(void* const* d_in, const int* in_sizes, int n_in,
                              void* d_out, int out_size, void* d_ws, size_t ws_size,
                              hipStream_t stream) {
  const float* x     = (const float*)d_in[0];
  const float* in_w  = (const float*)d_in[1];
  const float* in_b  = (const float*)d_in[2];
  const float* out_w = (const float*)d_in[3];
  const float* out_b = (const float*)d_in[4];
  const float* cb    = (const float*)d_in[5];
  float* out = (float*)d_out;

  char* ws = (char*)d_ws;
  double* P    = (double*)(ws + 0);            // 128 MB  [B][QC][T] fp64
  float*  zq   = (float*)(ws + 134217728);     //  64 MB  [B][QC][T] fp32
  double* Mcb  = (double*)(ws + 201326592);    //  16 MB  [q][p][K][CDIM] fp64
  double* cbn  = (double*)(ws + 218103808);    //   2 MB  [q][K][CDIM] fp64
  double* M    = (double*)(ws + 220200960);    // 512 KB  [q][p][32][32] fp64
  int*    idxw = (int*)   (ws + 220725248);    //   2 MB  [q][B*T] int
  double* vb   = (double*)(ws + 222822400);    //  16 KB
  double* obs  = (double*)(ws + 222838784);    //   8 KB
  double* lac  = (double*)(ws + 222846976);    //  64 B
  // w64 aliases the dead q=0 slabs of Mcb (stage 0 has no corrections -> never read)
  double* w64  = Mcb;                          //   2 MB  [QC][D] fp64

  float* out_q = out;                // [B][D][T]      67108864
  float* out_i = out + 67108864;     // [NUM_Q][B][T]    524288
  float* out_l = out + 67633152;     // [NUM_Q]               8

  k_cbn <<<dim3(32),  dim3(256), 0, stream>>>(cb, cbn);
  k_prep<<<dim3(4),   dim3(256), 0, stream>>>(out_b, obs, lac);
  k_w64 <<<dim3(1024),dim3(256), 0, stream>>>(in_w, w64);
  k_M   <<<dim3(256), dim3(256), 0, stream>>>(in_w, out_w, out_b, M, vb);
  k_Mcb <<<dim3(8192),dim3(256), 0, stream>>>(M, cb, Mcb);
  k_P   <<<dim3(QC/32, T/256, B), dim3(256), 0, stream>>>(x, w64, P);
  for (int q = 0; q < NUM_Q; ++q)
    k_stage<<<dim3(B*T/128), dim3(512), 0, stream>>>(q, P, Mcb, vb, in_b, cbn, cb,
                                                     idxw, zq, lac, out_i);
  k_out <<<dim3(D/16, T/(256*TT), B), dim3(256), 0, stream>>>(zq, out_w, obs, out_q);
  k_loss<<<dim3(1), dim3(64), 0, stream>>>(lac, out_l);
}

// Round 3
// 4470.311 us; speedup vs baseline: 1.4715x; 1.3115x over previous
//
#include <hip/hip_runtime.h>

#define NUM_Q 8
#define D     1024
#define CDIM  32
#define K     1024
#define B     16
#define T     4096
#define QC    (NUM_Q*CDIM)   // 256
#define EPSM  5e-4f          // fp32-scan margin; provable fp32 dot error <= ~2.4e-5

// ---------------- K0a: normalized codebook, fp64 (exact) + fp32 copy for fast scan --------
__global__ void k_cbn(const float* __restrict__ cb, double* __restrict__ cbn,
                      float* __restrict__ cbn32) {
  int i = blockIdx.x*blockDim.x + threadIdx.x;   // q*K + k
  if (i >= NUM_Q*K) return;
  const float* v = cb + (size_t)i*CDIM;
  double s = 0.0;
  for (int c = 0; c < CDIM; ++c) { double x = (double)v[c]; s += x*x; }
  double n = sqrt(s);
  n = fmax(n, 1e-12);
  double* o = cbn + (size_t)i*CDIM;
  float*  o32 = cbn32 + (size_t)i*CDIM;
  for (int c = 0; c < CDIM; ++c) {
    double r = (double)v[c] / n;
    o[c] = r;
    o32[c] = (float)r;
  }
}

// ---------------- K0b: zero loss accumulators + sum of out_b over stages ----------------
__global__ void k_prep(const float* __restrict__ out_b, double* __restrict__ obsum,
                       double* __restrict__ lossAcc) {
  int i = blockIdx.x*blockDim.x + threadIdx.x;
  if (i < NUM_Q) lossAcc[i] = 0.0;
  if (i < D) {
    double s = 0.0;
    for (int q = 0; q < NUM_Q; ++q) s += (double)out_b[q*D + i];
    obsum[i] = s;
  }
}

// ---------------- K0c: fp64 TRANSPOSED copy of in_w: w64t[d][j] (contiguous scalar reads) --
__global__ void k_w64(const float* __restrict__ in_w, double* __restrict__ w64t) {
  int i = blockIdx.x*blockDim.x + threadIdx.x;   // j*D + d, d fast -> coalesced read
  if (i < QC*D) {
    int j = i >> 10; int d = i & (D-1);
    w64t[(size_t)d*QC + j] = (double)in_w[i];
  }
}

// ---------------- K1a: M[q][p] = in_w[q] @ out_w[p]  (32x32, fp64), vb = in_w[q]@out_b[p] ----
__global__ void k_M(const float* __restrict__ in_w, const float* __restrict__ out_w,
                    const float* __restrict__ out_b, double* __restrict__ M,
                    double* __restrict__ vb) {
  int i = blockIdx.x*blockDim.x + threadIdx.x;   // 8*8*32*32 = 65536
  int e = i & 31; int c = (i >> 5) & 31; int p = (i >> 10) & 7; int q = i >> 13;
  if (q >= NUM_Q) return;
  const float* wi = in_w + ((size_t)q*CDIM + c)*D;
  const float* wo = out_w + (size_t)p*D*CDIM + e;
  double s = 0.0;
  for (int d = 0; d < D; ++d) s += (double)wi[d] * (double)wo[(size_t)d*CDIM];
  M[i] = s;
  if (e == 0) {
    const float* ob = out_b + (size_t)p*D;
    double sb = 0.0;
    for (int d = 0; d < D; ++d) sb += (double)wi[d] * (double)ob[d];
    vb[(q*8 + p)*CDIM + c] = sb;
  }
}

// ---------------- K1b: Mcb[q][p][k][c] = sum_e M[q][p][c][e] * cb[p][k][e] ----------------
// only pairs with 1<=q, p<q are ever read; q==0 slabs hold w64t, (1,1..4) hold cbn32.
__global__ void k_Mcb(const double* __restrict__ M, const float* __restrict__ cb,
                      double* __restrict__ Mcb) {
  long i = blockIdx.x*(long)blockDim.x + threadIdx.x;  // 8*8*1024*32 = 2097152
  if (i >= (long)NUM_Q*NUM_Q*K*CDIM) return;
  int c = (int)(i & 31); long r = i >> 5;
  int k = (int)(r & (K-1)); r >>= 10;
  int p = (int)(r & 7); int q = (int)(r >> 3);
  if (q == 0 || p >= q) return;                        // unused slabs repurposed
  const double* m = M + (((size_t)(q*8 + p)*CDIM + c)*CDIM);
  const float* v = cb + ((size_t)p*K + k)*CDIM;
  double s = 0.0;
  for (int e = 0; e < CDIM; ++e) s += m[e] * (double)v[e];
  Mcb[((size_t)(q*8 + p)*K + k)*CDIM + c] = s;
}

// ---------------- K2: P[b][j][t] = sum_d w64t[d][j] * x[b][d][t]  (fp64 accum) --------
// weights: wave-uniform contiguous rows -> s_load_dwordx16 stream; x: 4-deep reg dbuf.
__global__ __launch_bounds__(256, 4) void k_P(const float* __restrict__ x,
                                              const double* __restrict__ w64t,
                                              double* __restrict__ P) {
  int j0 = blockIdx.x*32;
  int t  = blockIdx.y*256 + threadIdx.x;
  int b  = blockIdx.z;
  double acc[32];
  #pragma unroll
  for (int j = 0; j < 32; ++j) acc[j] = 0.0;
  const float* xp = x + (size_t)b*D*T + t;
  float xb[4];
  #pragma unroll
  for (int u = 0; u < 4; ++u) xb[u] = xp[(size_t)u*T];
  for (int d0 = 0; d0 < D; d0 += 4) {
    float xn[4];
    if (d0 + 4 < D) {
      #pragma unroll
      for (int u = 0; u < 4; ++u) xn[u] = xp[(size_t)(d0 + 4 + u)*T];
    }
    #pragma unroll
    for (int u = 0; u < 4; ++u) {
      double xv = (double)xb[u];
      const double* wr = w64t + (size_t)(d0 + u)*QC + j0;
      #pragma unroll
      for (int jj = 0; jj < 32; ++jj) acc[jj] += xv * wr[jj];
    }
    #pragma unroll
    for (int u = 0; u < 4; ++u) xb[u] = xn[u];
  }
  double* Pp = P + ((size_t)b*QC + j0)*T + t;
  #pragma unroll
  for (int jj = 0; jj < 32; ++jj) Pp[(size_t)jj*T] = acc[jj];
}

// ---------------- K3: per-stage fused correction + fp32 scan (exact-fp64 argmax) ----------
// 4-way k-split; sg made wave-uniform via readfirstlane -> cbn32 reads scalarize.
// fp32 top-2 scan; margin < EPSM -> exact fp64 rescan (rare). Winner sim recomputed in
// fp64 (same 4-acc order) -> cross-group merge is exact fp64 -> indices bit-identical.
__global__ __launch_bounds__(512, 4) void k_stage(
    int q,
    const double* __restrict__ P, const double* __restrict__ Mcb,
    const double* __restrict__ vb, const float* __restrict__ in_b,
    const double* __restrict__ cbn, const float* __restrict__ cbn32,
    const float* __restrict__ cb,
    int* __restrict__ idx_ws, float* __restrict__ zq,
    double* __restrict__ lossAcc, float* __restrict__ out_idx) {
  __shared__ double bs[4][128];
  __shared__ int    bkk[4][128];
  const int tt = threadIdx.x & 127;
  const int sg = (int)(__builtin_amdgcn_readfirstlane(threadIdx.x) >> 7);  // uniform
  const int i  = blockIdx.x*128 + tt;     // b*T + t
  const int b  = i >> 12;
  const int t  = i & (T-1);

  double z[CDIM];
  {
    const double* Pp = P + ((size_t)b*QC + q*CDIM)*T + t;
    #pragma unroll
    for (int c = 0; c < CDIM; ++c) z[c] = Pp[(size_t)c*T] + (double)in_b[q*CDIM + c];
  }
  for (int p = 0; p < q; ++p) {
    int kp = idx_ws[(size_t)p*B*T + i];
    const double* mc  = Mcb + ((size_t)(q*8 + p)*K + kp)*CDIM;
    const double* vbp = vb + (q*8 + p)*CDIM;
    #pragma unroll
    for (int c = 0; c < CDIM; ++c) z[c] -= (mc[c] + vbp[c]);
  }
  float zf[CDIM];
  #pragma unroll
  for (int c = 0; c < CDIM; ++c) zf[c] = (float)z[c];

  // ---- fp32 scan over this group's 256 codes, tracking top-2 ----
  const float* c32 = cbn32 + ((size_t)q*K + (size_t)sg*(K/4))*CDIM;
  float best = -1e30f, second = -1e30f; int bi = 0;
  #pragma unroll 2
  for (int k = 0; k < K/4; ++k) {
    const float* r = c32 + (size_t)k*CDIM;
    float s0 = 0.f, s1 = 0.f, s2 = 0.f, s3 = 0.f;
    #pragma unroll
    for (int c = 0; c < CDIM; c += 4) {
      s0 += zf[c]*r[c]; s1 += zf[c+1]*r[c+1];
      s2 += zf[c+2]*r[c+2]; s3 += zf[c+3]*r[c+3];
    }
    float sim = (s0 + s1) + (s2 + s3);
    if (sim > best) { second = best; best = sim; bi = k; }
    else if (sim > second) { second = sim; }
  }

  // ---- exact fp64 winner ----
  const double* cbq = cbn + ((size_t)q*K + (size_t)sg*(K/4))*CDIM;
  double s64; int kwin = bi;
  if (best - second < EPSM) {
    // rare: fp32 could not separate top-2 -> exact fp64 rescan (first-occurrence)
    double b64 = -1e300; int b64i = 0;
    for (int k = 0; k < K/4; ++k) {
      const double* r = cbq + (size_t)k*CDIM;
      double u0 = 0.0, u1 = 0.0, u2 = 0.0, u3 = 0.0;
      #pragma unroll
      for (int c = 0; c < CDIM; c += 4) {
        u0 += z[c]*r[c]; u1 += z[c+1]*r[c+1];
        u2 += z[c+2]*r[c+2]; u3 += z[c+3]*r[c+3];
      }
      double sd = (u0 + u1) + (u2 + u3);
      if (sd > b64) { b64 = sd; b64i = k; }
    }
    s64 = b64; kwin = b64i;
  } else {
    const double* r = cbq + (size_t)kwin*CDIM;
    double u0 = 0.0, u1 = 0.0, u2 = 0.0, u3 = 0.0;
    #pragma unroll
    for (int c = 0; c < CDIM; c += 4) {
      u0 += z[c]*r[c]; u1 += z[c+1]*r[c+1];
      u2 += z[c+2]*r[c+2]; u3 += z[c+3]*r[c+3];
    }
    s64 = (u0 + u1) + (u2 + u3);
  }
  bs[sg][tt]  = s64;
  bkk[sg][tt] = sg*(K/4) + kwin;
  __syncthreads();

  if (sg == 0) {
    double bb = bs[0][tt]; int kbest = bkk[0][tt];
    #pragma unroll
    for (int g = 1; g < 4; ++g) {            // ascending group + strict > == global
      if (bs[g][tt] > bb) { bb = bs[g][tt]; kbest = bkk[g][tt]; }   // first-occurrence
    }
    idx_ws[(size_t)q*B*T + i] = kbest;
    out_idx[(size_t)q*B*T + i] = (float)kbest;

    const float* cv = cb + ((size_t)q*K + kbest)*CDIM;
    float* zp = zq + ((size_t)b*QC + q*CDIM)*T + t;
    double l = 0.0;
    #pragma unroll
    for (int c = 0; c < CDIM; ++c) {
      float f = cv[c];
      zp[(size_t)c*T] = f;
      double d2 = z[c] - (double)f;
      l += d2*d2;
    }
    for (int off = 32; off > 0; off >>= 1) l += __shfl_down(l, off, 64);
    if ((threadIdx.x & 63) == 0) atomicAdd(&lossAcc[q], l);
  }
}

// ---------------- K4: quantized_out = out_w_cat @ zq_cat + obsum  (fp32) -------------------
#define TT 4
__global__ __launch_bounds__(256) void k_out(const float* __restrict__ zq,
                                             const float* __restrict__ out_w,
                                             const double* __restrict__ obsum,
                                             float* __restrict__ out) {
  __shared__ float lw[QC][16];            // 16 KB, [j][d-sub] -> b128 broadcast reads
  int d0 = blockIdx.x*16;                 // d-tile on x -> consecutive blocks reuse zq tile
  int t0 = blockIdx.y*(256*TT);
  int b  = blockIdx.z;
  for (int u = threadIdx.x; u < 16*QC; u += 256) {
    int j = u >> 4; int a = u & 15;
    lw[j][a] = out_w[(size_t)(j >> 5)*D*CDIM + (size_t)(d0 + a)*CDIM + (j & 31)];
  }
  __syncthreads();
  float acc[16][TT];
  #pragma unroll
  for (int a = 0; a < 16; ++a)
    #pragma unroll
    for (int u = 0; u < TT; ++u) acc[a][u] = 0.f;
  const float* zp = zq + (size_t)b*QC*T + t0 + threadIdx.x;
  for (int j = 0; j < QC; ++j) {
    float zv[TT];
    #pragma unroll
    for (int u = 0; u < TT; ++u) zv[u] = zp[(size_t)j*T + u*256];
    #pragma unroll
    for (int a4 = 0; a4 < 4; ++a4) {
      float4 w = *(const float4*)&lw[j][a4*4];
      #pragma unroll
      for (int u = 0; u < TT; ++u) {
        acc[a4*4+0][u] += w.x*zv[u];
        acc[a4*4+1][u] += w.y*zv[u];
        acc[a4*4+2][u] += w.z*zv[u];
        acc[a4*4+3][u] += w.w*zv[u];
      }
    }
  }
  for (int a = 0; a < 16; ++a) {
    float bb = (float)obsum[d0 + a];
    float* op = out + ((size_t)b*D + d0 + a)*T + t0 + threadIdx.x;
    #pragma unroll
    for (int u = 0; u < TT; ++u) op[(size_t)u*256] = acc[a][u] + bb;
  }
}

// ---------------- K5: losses -> d_out ----------------
__global__ void k_loss(const double* __restrict__ lossAcc, float* __restrict__ out_l) {
  int i = threadIdx.x;
  if (i < NUM_Q)
    out_l[i] = (float)(1.25 * lossAcc[i] / ((double)B * CDIM * T));
}

extern "C" void kernel_launch(void* const* d_in, const int* in_sizes, int n_in,
                              void* d_out, int out_size, void* d_ws, size_t ws_size,
                              hipStream_t stream) {
  const float* x     = (const float*)d_in[0];
  const float* in_w  = (const float*)d_in[1];
  const float* in_b  = (const float*)d_in[2];
  const float* out_w = (const float*)d_in[3];
  const float* out_b = (const float*)d_in[4];
  const float* cb    = (const float*)d_in[5];
  float* out = (float*)d_out;

  char* ws = (char*)d_ws;
  double* P    = (double*)(ws + 0);            // 128 MB  [B][QC][T] fp64
  float*  zq   = (float*)(ws + 134217728);     //  64 MB  [B][QC][T] fp32
  double* Mcb  = (double*)(ws + 201326592);    //  16 MB  [q][p][K][CDIM] fp64
  double* cbn  = (double*)(ws + 218103808);    //   2 MB  [q][K][CDIM] fp64
  double* M    = (double*)(ws + 220200960);    // 512 KB  [q][p][32][32] fp64
  int*    idxw = (int*)   (ws + 220725248);    //   2 MB  [q][B*T] int
  double* vb   = (double*)(ws + 222822400);    //  16 KB
  double* obs  = (double*)(ws + 222838784);    //   8 KB
  double* lac  = (double*)(ws + 222846976);    //  64 B
  // dead-Mcb-slab reuse (k_Mcb skips q==0 and p>=q; k_stage reads only p<q):
  double* w64t = Mcb;                                   // 2 MB: q=0 slabs  [D][QC] fp64
  float*  cb32 = (float*)(ws + 203685888);              // 1 MB: (q=1,p=1..4) slabs

  float* out_q = out;                // [B][D][T]      67108864
  float* out_i = out + 67108864;     // [NUM_Q][B][T]    524288
  float* out_l = out + 67633152;     // [NUM_Q]               8

  k_cbn <<<dim3(32),  dim3(256), 0, stream>>>(cb, cbn, cb32);
  k_prep<<<dim3(4),   dim3(256), 0, stream>>>(out_b, obs, lac);
  k_w64 <<<dim3(1024),dim3(256), 0, stream>>>(in_w, w64t);
  k_M   <<<dim3(256), dim3(256), 0, stream>>>(in_w, out_w, out_b, M, vb);
  k_Mcb <<<dim3(8192),dim3(256), 0, stream>>>(M, cb, Mcb);
  k_P   <<<dim3(QC/32, T/256, B), dim3(256), 0, stream>>>(x, w64t, P);
  for (int q = 0; q < NUM_Q; ++q)
    k_stage<<<dim3(B*T/128), dim3(512), 0, stream>>>(q, P, Mcb, vb, in_b, cbn, cb32, cb,
                                                     idxw, zq, lac, out_i);
  k_out <<<dim3(D/16, T/(256*TT), B), dim3(256), 0, stream>>>(zq, out_w, obs, out_q);
  k_loss<<<dim3(1), dim3(64), 0, stream>>>(lac, out_l);
}